// Round 11
// baseline (353.191 us; speedup 1.0000x reference)
//
#include <hip/hip_runtime.h>
#include <hip/hip_bf16.h>
#include <hip/hip_fp16.h>

#define N_NODES  100000
#define N_EDGES  1600000
#define N_GRAPHS 64
// IN_CH = HIDDEN = 128, OUT_CH = 2

// Sort geometry: 256 buckets x 391 cols, 391 blocks x 4096 edges
#define NB       256
#define BSZ      391          // cols per bucket (256*391 >= 100000); fits 9 bits
#define NE4      (N_EDGES/4)
#define NBLK     391
#define ROWMASK  0x1FFFF      // 17 bits, N_NODES < 131072

typedef __attribute__((ext_vector_type(4))) float    f32x4;
typedef __attribute__((ext_vector_type(8))) _Float16 f16x8;

// ---------------------------------------------------------------------------
// Pass A1: per-block 256-bucket histogram of col
__global__ __launch_bounds__(256) void sortcount_kernel(const int4* __restrict__ col4,
                                                        int* __restrict__ blockcnt) {
    __shared__ int hist[NB];
    int t = threadIdx.x, blk = blockIdx.x;
    hist[t] = 0;
    __syncthreads();
#pragma unroll
    for (int j = 0; j < 4; ++j) {
        int i = blk * 1024 + j * 256 + t;
        if (i < NE4) {
            int4 c = col4[i];
            atomicAdd(&hist[c.x / BSZ], 1);
            atomicAdd(&hist[c.y / BSZ], 1);
            atomicAdd(&hist[c.z / BSZ], 1);
            atomicAdd(&hist[c.w / BSZ], 1);
        }
    }
    __syncthreads();
    blockcnt[blk * NB + t] = hist[t];
}

// Pass A2a: per-bucket exclusive scan across blocks
__global__ __launch_bounds__(256) void sortscan_kernel(int* __restrict__ blockcnt,
                                                       int* __restrict__ buckettotal) {
    int b = blockIdx.x, t = threadIdx.x;
    __shared__ int sc[256];
    int e0 = 2 * t, e1 = 2 * t + 1;
    int v0 = (e0 < NBLK) ? blockcnt[e0 * NB + b] : 0;
    int v1 = (e1 < NBLK) ? blockcnt[e1 * NB + b] : 0;
    int ps = v0 + v1;
    sc[t] = ps;
    __syncthreads();
    for (int d = 1; d < 256; d <<= 1) {
        int x = (t >= d) ? sc[t - d] : 0;
        __syncthreads();
        sc[t] += x;
        __syncthreads();
    }
    int ex = sc[t] - ps;
    if (e0 < NBLK) blockcnt[e0 * NB + b] = ex;
    if (e1 < NBLK) blockcnt[e1 * NB + b] = ex + v0;
    if (t == 255) buckettotal[b] = sc[255];
}

// Pass A2b: scan of bucket totals
__global__ __launch_bounds__(256) void sortbase_kernel(const int* __restrict__ buckettotal,
                                                       int* __restrict__ bucket_base,
                                                       int* __restrict__ off) {
    __shared__ int sc[256];
    int t = threadIdx.x;
    int v = buckettotal[t];
    sc[t] = v;
    __syncthreads();
    for (int d = 1; d < 256; d <<= 1) {
        int x = (t >= d) ? sc[t - d] : 0;
        __syncthreads();
        sc[t] += x;
        __syncthreads();
    }
    bucket_base[t] = sc[t] - v;
    if (t == 255) {
        bucket_base[256] = sc[255];
        off[N_NODES] = N_EDGES;
    }
}

// Pass A3: scatter packed (localcol<<17 | row) into bucket-grouped buffer
__global__ __launch_bounds__(256) void sortscatter_kernel(const int4* __restrict__ row4,
                                                          const int4* __restrict__ col4,
                                                          const int* __restrict__ blockpre,
                                                          const int* __restrict__ bucket_base,
                                                          int* __restrict__ pairs) {
    __shared__ int cur[NB];
    int t = threadIdx.x, blk = blockIdx.x;
    cur[t] = bucket_base[t] + blockpre[blk * NB + t];
    __syncthreads();
#pragma unroll
    for (int j = 0; j < 4; ++j) {
        int i = blk * 1024 + j * 256 + t;
        if (i < NE4) {
            int4 r = row4[i];
            int4 c = col4[i];
            int b0 = c.x / BSZ, b1 = c.y / BSZ, b2 = c.z / BSZ, b3 = c.w / BSZ;
            int p0 = atomicAdd(&cur[b0], 1); pairs[p0] = ((c.x - b0 * BSZ) << 17) | r.x;
            int p1 = atomicAdd(&cur[b1], 1); pairs[p1] = ((c.y - b1 * BSZ) << 17) | r.y;
            int p2 = atomicAdd(&cur[b2], 1); pairs[p2] = ((c.z - b2 * BSZ) << 17) | r.z;
            int p3 = atomicAdd(&cur[b3], 1); pairs[p3] = ((c.w - b3 * BSZ) << 17) | r.w;
        }
    }
}

// Pass B: per-bucket local sort -> sortr, off, dinv
__global__ __launch_bounds__(256) void sortlocal_kernel(const int* __restrict__ pairs,
                                                        const int* __restrict__ bucket_base,
                                                        const int* __restrict__ buckettotal,
                                                        int* __restrict__ sortr,
                                                        int* __restrict__ off,
                                                        float* __restrict__ dinv) {
    int b = blockIdx.x, t = threadIdx.x;
    int base = bucket_base[b];
    int cnt  = buckettotal[b];
    int c0   = b * BSZ;
    int nc   = N_NODES - c0; if (nc > BSZ) nc = BSZ;

    __shared__ int hist[BSZ];
    __shared__ int sc[256];
    for (int i = t; i < nc; i += 256) hist[i] = 0;
    __syncthreads();
    for (int i = t; i < cnt; i += 256) {
        int pc = pairs[base + i];
        atomicAdd(&hist[pc >> 17], 1);
    }
    __syncthreads();
    int e0 = 2 * t, e1 = 2 * t + 1;
    int h0 = (e0 < nc) ? hist[e0] : 0;
    int h1 = (e1 < nc) ? hist[e1] : 0;
    int ps = h0 + h1;
    sc[t] = ps;
    __syncthreads();
    for (int d = 1; d < 256; d <<= 1) {
        int x = (t >= d) ? sc[t - d] : 0;
        __syncthreads();
        sc[t] += x;
        __syncthreads();
    }
    int ex = sc[t] - ps;
    if (e0 < nc) { off[c0 + e0] = base + ex;      dinv[c0 + e0] = rsqrtf((float)h0 + 1.f); }
    if (e1 < nc) { off[c0 + e1] = base + ex + h0; dinv[c0 + e1] = rsqrtf((float)h1 + 1.f); }
    __syncthreads();
    if (e0 < nc) hist[e0] = base + ex;
    if (e1 < nc) hist[e1] = base + ex + h0;
    __syncthreads();
    for (int i = t; i < cnt; i += 256) {
        int pc = pairs[base + i];
        int pos = atomicAdd(&hist[pc >> 17], 1);
        sortr[pos] = pc & ROWMASK;
    }
}

// ---------------------------------------------------------------------------
// W pre-pack (fragment-major fp16 for mfma_f32_16x16x32_f16) + zero pooled/gcnt
__global__ __launch_bounds__(256) void wpack_zero_kernel(const float* __restrict__ W1,
                                                         const float* __restrict__ W2,
                                                         _Float16* __restrict__ Wp1,
                                                         _Float16* __restrict__ Wp2,
                                                         float* __restrict__ pooled,
                                                         float* __restrict__ gcnt) {
    int tid = blockIdx.x * 256 + threadIdx.x;   // 0..4095
    for (int i = tid; i < N_GRAPHS * 128 + N_GRAPHS; i += 4096) {
        if (i < N_GRAPHS * 128) pooled[i] = 0.f;
        else gcnt[i - N_GRAPHS * 128] = 0.f;
    }
    const float* W = (tid < 2048) ? W1 : W2;
    _Float16*   Wp = (tid < 2048) ? Wp1 : Wp2;
    int t = tid & 2047;
    int f = t >> 6, lane = t & 63;
    int j = f >> 2, s = f & 3;
    int kb = s * 32 + (lane >> 4) * 8;
    int c  = j * 16 + (lane & 15);
#pragma unroll
    for (int i = 0; i < 8; ++i)
        Wp[(size_t)t * 8 + i] = (_Float16)W[(kb + i) * 128 + c];
}

// ---------------------------------------------------------------------------
// MFMA GEMM layer1: hs[n][:] = fp16( dinv[n] * (X[n][:] @ W1) ), X fp32
__global__ __launch_bounds__(256) void gemm_mfma_kernel(const float* __restrict__ X,
                                                        const _Float16* __restrict__ Wp,
                                                        const float* __restrict__ dinv,
                                                        _Float16* __restrict__ out) {
    __shared__ _Float16 Wl[16384];
    {
        const float4* src = (const float4*)Wp;
        float4* dst = (float4*)Wl;
        for (int i = threadIdx.x; i < 2048; i += 256) dst[i] = src[i];
    }
    __syncthreads();

    int wv = threadIdx.x >> 6, lane = threadIdx.x & 63;
    int tile = blockIdx.x * 4 + wv;
    if (tile >= N_NODES / 16) return;
    int n0 = tile * 16;
    int m = lane & 15, b = lane >> 4;

    f16x8 a[4];
    const float* base = X + (size_t)(n0 + m) * 128 + b * 8;
#pragma unroll
    for (int s = 0; s < 4; ++s) {
        float4 u = *(const float4*)(base + s * 32);
        float4 v = *(const float4*)(base + s * 32 + 4);
        f16x8 tt;
        tt[0] = (_Float16)u.x; tt[1] = (_Float16)u.y;
        tt[2] = (_Float16)u.z; tt[3] = (_Float16)u.w;
        tt[4] = (_Float16)v.x; tt[5] = (_Float16)v.y;
        tt[6] = (_Float16)v.z; tt[7] = (_Float16)v.w;
        a[s] = tt;
    }

    f32x4 acc[8];
#pragma unroll
    for (int j = 0; j < 8; ++j) acc[j] = (f32x4){0.f, 0.f, 0.f, 0.f};
#pragma unroll
    for (int j = 0; j < 8; ++j)
#pragma unroll
        for (int s = 0; s < 4; ++s) {
            f16x8 bf = *(const f16x8*)&Wl[(j * 4 + s) * 512 + lane * 8];
            acc[j] = __builtin_amdgcn_mfma_f32_16x16x32_f16(a[s], bf, acc[j], 0, 0, 0);
        }

    float dv0 = dinv[n0 + b * 4 + 0];
    float dv1 = dinv[n0 + b * 4 + 1];
    float dv2 = dinv[n0 + b * 4 + 2];
    float dv3 = dinv[n0 + b * 4 + 3];
#pragma unroll
    for (int j = 0; j < 8; ++j) {
        _Float16* o = out + (size_t)(n0 + b * 4) * 128 + j * 16 + m;
        o[0 * 128] = (_Float16)(acc[j][0] * dv0);
        o[1 * 128] = (_Float16)(acc[j][1] * dv1);
        o[2 * 128] = (_Float16)(acc[j][2] * dv2);
        o[3 * 128] = (_Float16)(acc[j][3] * dv3);
    }
}

// ---------------------------------------------------------------------------
// Gather-accumulate one target row (float2 per lane) from fp16 messages
__device__ __forceinline__ float2 gather_row(const __half* __restrict__ hs,
                                             const int* __restrict__ sortr,
                                             int c, int e0, int e1, long chb) {
    float2 s = __half22float2(*(const __half2*)&hs[(long)c * 128 + chb]);
    float a0x = s.x, a0y = s.y;
    float a1x = 0.f, a1y = 0.f, a2x = 0.f, a2y = 0.f, a3x = 0.f, a3y = 0.f;
    int e = e0;
    for (; e + 4 <= e1; e += 4) {
        int r0 = sortr[e + 0], r1 = sortr[e + 1];
        int r2 = sortr[e + 2], r3 = sortr[e + 3];
        float2 v0 = __half22float2(*(const __half2*)&hs[(long)r0 * 128 + chb]);
        float2 v1 = __half22float2(*(const __half2*)&hs[(long)r1 * 128 + chb]);
        float2 v2 = __half22float2(*(const __half2*)&hs[(long)r2 * 128 + chb]);
        float2 v3 = __half22float2(*(const __half2*)&hs[(long)r3 * 128 + chb]);
        a0x += v0.x; a0y += v0.y;
        a1x += v1.x; a1y += v1.y;
        a2x += v2.x; a2y += v2.y;
        a3x += v3.x; a3y += v3.y;
    }
    for (; e < e1; ++e) {
        int r0 = sortr[e];
        float2 v0 = __half22float2(*(const __half2*)&hs[(long)r0 * 128 + chb]);
        a0x += v0.x; a0y += v0.y;
    }
    float2 r;
    r.x = (a0x + a1x) + (a2x + a3x);
    r.y = (a0y + a1y) + (a2y + a3y);
    return r;
}

// ---------------------------------------------------------------------------
// Fused agg(layer1) + gemm(W2): block = 1024 threads = 16 waves, 16 targets.
// Each wave gathers ONE target row (restores 1-wave-per-node latency hiding),
// then waves 0-7 run the 16x128 @ 128x128 MFMA against W2.
__global__ __launch_bounds__(1024) void agg_gemm_kernel(const __half* __restrict__ hs,
                                                        const int* __restrict__ sortr,
                                                        const int* __restrict__ off,
                                                        const float* __restrict__ dinv,
                                                        const float* __restrict__ bias,   // b1
                                                        const _Float16* __restrict__ Wp,  // W2 packed
                                                        _Float16* __restrict__ out) {
    __shared__ float rowbuf[16 * 132];   // stride 132: 16B-aligned rows
    int t = threadIdx.x;
    int wv = t >> 6, lane = t & 63;
    int c0 = blockIdx.x * 16;
    const long chb = 2 * (long)lane;
    float2 bb = *(const float2*)&bias[chb];

    {
        int c = c0 + wv;
        float2 g = gather_row(hs, sortr, c, off[c], off[c + 1], chb);
        float dv = dinv[c];
        rowbuf[wv * 132 + 2 * lane]     = fmaxf(fmaf(g.x, dv, bb.x), 0.f);
        rowbuf[wv * 132 + 2 * lane + 1] = fmaxf(fmaf(g.y, dv, bb.y), 0.f);
    }
    __syncthreads();

    if (wv < 8) {
        int m = lane & 15, b = lane >> 4;
        f16x8 a[4];
#pragma unroll
        for (int s = 0; s < 4; ++s) {
            const float* rb = &rowbuf[m * 132 + s * 32 + b * 8];
            float4 u = *(const float4*)rb;
            float4 v = *(const float4*)(rb + 4);
            f16x8 tt;
            tt[0] = (_Float16)u.x; tt[1] = (_Float16)u.y;
            tt[2] = (_Float16)u.z; tt[3] = (_Float16)u.w;
            tt[4] = (_Float16)v.x; tt[5] = (_Float16)v.y;
            tt[6] = (_Float16)v.z; tt[7] = (_Float16)v.w;
            a[s] = tt;
        }

        f32x4 acc = (f32x4){0.f, 0.f, 0.f, 0.f};
        const int j = wv;
#pragma unroll
        for (int s = 0; s < 4; ++s) {
            f16x8 bf = *(const f16x8*)&Wp[((size_t)(j * 4 + s) * 64 + lane) * 8];
            acc = __builtin_amdgcn_mfma_f32_16x16x32_f16(a[s], bf, acc, 0, 0, 0);
        }

        float dv0 = dinv[c0 + b * 4 + 0];
        float dv1 = dinv[c0 + b * 4 + 1];
        float dv2 = dinv[c0 + b * 4 + 2];
        float dv3 = dinv[c0 + b * 4 + 3];
        _Float16* o = out + (size_t)(c0 + b * 4) * 128 + j * 16 + m;
        o[0 * 128] = (_Float16)(acc[0] * dv0);
        o[1 * 128] = (_Float16)(acc[1] * dv1);
        o[2 * 128] = (_Float16)(acc[2] * dv2);
        o[3 * 128] = (_Float16)(acc[3] * dv3);
    }
}

// ---------------------------------------------------------------------------
// Fused agg(layer2) + mean-pool: block = 1024 threads = 16 waves, 16 targets.
// Each wave gathers+relus ONE row into LDS; threads 0-127 column-reduce.
__global__ __launch_bounds__(1024) void agg_pool_kernel(const __half* __restrict__ hs2,
                                                        const int* __restrict__ sortr,
                                                        const int* __restrict__ off,
                                                        const float* __restrict__ dinv,
                                                        const float* __restrict__ bias,  // b2
                                                        const int* __restrict__ batch,
                                                        float* __restrict__ pooled,
                                                        float* __restrict__ gcnt) {
    __shared__ float rowbuf[16 * 132];
    __shared__ int gb[16];
    int t = threadIdx.x;
    int wv = t >> 6, lane = t & 63;
    int c0 = blockIdx.x * 16;
    const long chb = 2 * (long)lane;
    float2 bb = *(const float2*)&bias[chb];

    {
        int c = c0 + wv;
        float2 g = gather_row(hs2, sortr, c, off[c], off[c + 1], chb);
        float dv = dinv[c];
        rowbuf[wv * 132 + 2 * lane]     = fmaxf(fmaf(g.x, dv, bb.x), 0.f);
        rowbuf[wv * 132 + 2 * lane + 1] = fmaxf(fmaf(g.y, dv, bb.y), 0.f);
        if (lane == 0) gb[wv] = batch[c];
    }
    __syncthreads();

    if (t < 128) {
        int g0   = gb[0];
        int gend = gb[15];
        bool slow = (gend > g0 + 1);   // block spans >2 graphs (defensive; ~never)
        if (!slow) {
            float sA = 0.f, sB = 0.f;
#pragma unroll
            for (int r = 0; r < 16; ++r) {
                float v = rowbuf[r * 132 + t];
                if (gb[r] == g0) sA += v; else sB += v;
            }
            atomicAdd(&pooled[(size_t)g0 * 128 + t], sA);
            if (gend != g0) atomicAdd(&pooled[(size_t)gend * 128 + t], sB);
            if (t == 0) {
                int nA = 0;
#pragma unroll
                for (int r = 0; r < 16; ++r) nA += (gb[r] == g0) ? 1 : 0;
                atomicAdd(&gcnt[g0], (float)nA);
                if (gend != g0) atomicAdd(&gcnt[gend], (float)(16 - nA));
            }
        } else {
            for (int r = 0; r < 16; ++r)
                atomicAdd(&pooled[(size_t)gb[r] * 128 + t], rowbuf[r * 132 + t]);
            if (t == 0)
                for (int r = 0; r < 16; ++r) atomicAdd(&gcnt[gb[r]], 1.f);
        }
    }
}

// final: out[g][o] = (pooled[g][:]/cnt) @ Wlin[:,o] + blin[o]
__global__ void final_kernel(const float* __restrict__ pooled,
                             const float* __restrict__ gcnt,
                             const float* __restrict__ Wlin,
                             const float* __restrict__ blin,
                             float* __restrict__ out) {
    int t = threadIdx.x;
    if (t >= N_GRAPHS * 2) return;
    int g = t >> 1, o = t & 1;
    float c = gcnt[g];
    if (c < 1.f) c = 1.f;
    float s = 0.f;
    for (int k = 0; k < 128; ++k)
        s += (pooled[g * 128 + k] / c) * Wlin[k * 2 + o];
    out[g * 2 + o] = s + blin[o];
}

// ---------------------------------------------------------------------------
extern "C" void kernel_launch(void* const* d_in, const int* in_sizes, int n_in,
                              void* d_out, int out_size, void* d_ws, size_t ws_size,
                              hipStream_t stream) {
    const float* x     = (const float*)d_in[0];
    const int*   row   = (const int*)d_in[1];
    const int*   col   = row + N_EDGES;
    const int*   batch = (const int*)d_in[2];
    const float* W1    = (const float*)d_in[3];
    const float* b1    = (const float*)d_in[4];
    const float* W2    = (const float*)d_in[5];
    const float* b2    = (const float*)d_in[6];
    const float* Wlin  = (const float*)d_in[7];
    const float* blin  = (const float*)d_in[8];
    float* out = (float*)d_out;

    char* w = (char*)d_ws;
    size_t p = 0;
    auto alloc = [&](size_t bytes) -> void* {
        void* r = w + p;
        p += (bytes + 511) & ~(size_t)511;
        return r;
    };
    int*      off         = (int*)alloc((size_t)(N_NODES + 1) * 4);
    float*    dinv        = (float*)alloc((size_t)N_NODES * 4);
    int*      sortr       = (int*)alloc((size_t)N_EDGES * 4);
    int*      pairs       = (int*)alloc((size_t)N_EDGES * 4);
    int*      blockcnt    = (int*)alloc((size_t)NBLK * NB * 4);
    int*      buckettotal = (int*)alloc((size_t)NB * 4);
    int*      bucket_base = (int*)alloc((size_t)(NB + 1) * 4);
    _Float16* Wp1         = (_Float16*)alloc((size_t)128 * 128 * 2);
    _Float16* Wp2         = (_Float16*)alloc((size_t)128 * 128 * 2);
    __half*   hs          = (__half*)alloc((size_t)N_NODES * 128 * 2);
    __half*   hs2         = (__half*)alloc((size_t)N_NODES * 128 * 2);
    float*    pooled      = (float*)alloc((size_t)N_GRAPHS * 128 * 4);
    float*    gcnt        = (float*)alloc((size_t)N_GRAPHS * 4);
    (void)ws_size; (void)in_sizes; (void)n_in; (void)out_size;

    // CSR build (deterministic binned counting sort) + weight pack + zero
    sortcount_kernel<<<NBLK, 256, 0, stream>>>((const int4*)col, blockcnt);
    sortscan_kernel<<<NB, 256, 0, stream>>>(blockcnt, buckettotal);
    sortbase_kernel<<<1, 256, 0, stream>>>(buckettotal, bucket_base, off);
    sortscatter_kernel<<<NBLK, 256, 0, stream>>>((const int4*)row, (const int4*)col,
                                                 blockcnt, bucket_base, pairs);
    sortlocal_kernel<<<NB, 256, 0, stream>>>(pairs, bucket_base, buckettotal,
                                             sortr, off, dinv);
    wpack_zero_kernel<<<16, 256, 0, stream>>>(W1, W2, Wp1, Wp2, pooled, gcnt);

    // layer 1 GEMM (MFMA, dinv premul)
    gemm_mfma_kernel<<<(N_NODES / 16 + 3) / 4, 256, 0, stream>>>(x, Wp1, dinv, (_Float16*)hs);
    // fused agg1 + gemm2  (16 waves/block, 1 wave per target row)
    agg_gemm_kernel<<<N_NODES / 16, 1024, 0, stream>>>(hs, sortr, off, dinv, b1, Wp2,
                                                       (_Float16*)hs2);
    // fused agg2 + mean-pool accumulate  (16 waves/block, 1 wave per target row)
    agg_pool_kernel<<<N_NODES / 16, 1024, 0, stream>>>(hs2, sortr, off, dinv, b2, batch,
                                                       pooled, gcnt);
    // classifier
    final_kernel<<<1, 128, 0, stream>>>(pooled, gcnt, Wlin, blin, out);
}

// Round 12
// 337.761 us; speedup vs baseline: 1.0457x; 1.0457x over previous
//
#include <hip/hip_runtime.h>
#include <hip/hip_bf16.h>
#include <hip/hip_fp16.h>

#define N_NODES  100000
#define N_EDGES  1600000
#define N_GRAPHS 64
// IN_CH = HIDDEN = 128, OUT_CH = 2

// Sort geometry: 256 buckets x 391 cols, 391 blocks x 4096 edges
#define NB       256
#define BSZ      391          // cols per bucket (256*391 >= 100000); fits 9 bits
#define NE4      (N_EDGES/4)
#define NBLK     391
#define ROWMASK  0x1FFFF      // 17 bits, N_NODES < 131072

typedef __attribute__((ext_vector_type(4))) float    f32x4;
typedef __attribute__((ext_vector_type(2))) float    f32x2;
typedef __attribute__((ext_vector_type(8))) _Float16 f16x8;

// fp8 e4m3 (OCP on gfx950) encode/decode via HW cvt
__device__ __forceinline__ unsigned char enc8(float v) {
    return (unsigned char)(__builtin_amdgcn_cvt_pk_fp8_f32(v, v, 0, false) & 0xFF);
}
__device__ __forceinline__ f32x2 dec8x2(unsigned short us) {
    return __builtin_amdgcn_cvt_pk_f32_fp8((unsigned int)us, false);
}

// ---------------------------------------------------------------------------
// Pass A1: per-block 256-bucket histogram of col
__global__ __launch_bounds__(256) void sortcount_kernel(const int4* __restrict__ col4,
                                                        int* __restrict__ blockcnt) {
    __shared__ int hist[NB];
    int t = threadIdx.x, blk = blockIdx.x;
    hist[t] = 0;
    __syncthreads();
#pragma unroll
    for (int j = 0; j < 4; ++j) {
        int i = blk * 1024 + j * 256 + t;
        if (i < NE4) {
            int4 c = col4[i];
            atomicAdd(&hist[c.x / BSZ], 1);
            atomicAdd(&hist[c.y / BSZ], 1);
            atomicAdd(&hist[c.z / BSZ], 1);
            atomicAdd(&hist[c.w / BSZ], 1);
        }
    }
    __syncthreads();
    blockcnt[blk * NB + t] = hist[t];
}

// Pass A2a: per-bucket exclusive scan across blocks
__global__ __launch_bounds__(256) void sortscan_kernel(int* __restrict__ blockcnt,
                                                       int* __restrict__ buckettotal) {
    int b = blockIdx.x, t = threadIdx.x;
    __shared__ int sc[256];
    int e0 = 2 * t, e1 = 2 * t + 1;
    int v0 = (e0 < NBLK) ? blockcnt[e0 * NB + b] : 0;
    int v1 = (e1 < NBLK) ? blockcnt[e1 * NB + b] : 0;
    int ps = v0 + v1;
    sc[t] = ps;
    __syncthreads();
    for (int d = 1; d < 256; d <<= 1) {
        int x = (t >= d) ? sc[t - d] : 0;
        __syncthreads();
        sc[t] += x;
        __syncthreads();
    }
    int ex = sc[t] - ps;
    if (e0 < NBLK) blockcnt[e0 * NB + b] = ex;
    if (e1 < NBLK) blockcnt[e1 * NB + b] = ex + v0;
    if (t == 255) buckettotal[b] = sc[255];
}

// Pass A2b: scan of bucket totals
__global__ __launch_bounds__(256) void sortbase_kernel(const int* __restrict__ buckettotal,
                                                       int* __restrict__ bucket_base,
                                                       int* __restrict__ off) {
    __shared__ int sc[256];
    int t = threadIdx.x;
    int v = buckettotal[t];
    sc[t] = v;
    __syncthreads();
    for (int d = 1; d < 256; d <<= 1) {
        int x = (t >= d) ? sc[t - d] : 0;
        __syncthreads();
        sc[t] += x;
        __syncthreads();
    }
    bucket_base[t] = sc[t] - v;
    if (t == 255) {
        bucket_base[256] = sc[255];
        off[N_NODES] = N_EDGES;
    }
}

// Pass A3: scatter packed (localcol<<17 | row) into bucket-grouped buffer
__global__ __launch_bounds__(256) void sortscatter_kernel(const int4* __restrict__ row4,
                                                          const int4* __restrict__ col4,
                                                          const int* __restrict__ blockpre,
                                                          const int* __restrict__ bucket_base,
                                                          int* __restrict__ pairs) {
    __shared__ int cur[NB];
    int t = threadIdx.x, blk = blockIdx.x;
    cur[t] = bucket_base[t] + blockpre[blk * NB + t];
    __syncthreads();
#pragma unroll
    for (int j = 0; j < 4; ++j) {
        int i = blk * 1024 + j * 256 + t;
        if (i < NE4) {
            int4 r = row4[i];
            int4 c = col4[i];
            int b0 = c.x / BSZ, b1 = c.y / BSZ, b2 = c.z / BSZ, b3 = c.w / BSZ;
            int p0 = atomicAdd(&cur[b0], 1); pairs[p0] = ((c.x - b0 * BSZ) << 17) | r.x;
            int p1 = atomicAdd(&cur[b1], 1); pairs[p1] = ((c.y - b1 * BSZ) << 17) | r.y;
            int p2 = atomicAdd(&cur[b2], 1); pairs[p2] = ((c.z - b2 * BSZ) << 17) | r.z;
            int p3 = atomicAdd(&cur[b3], 1); pairs[p3] = ((c.w - b3 * BSZ) << 17) | r.w;
        }
    }
}

// Pass B: per-bucket local sort -> sortr, off, dinv
__global__ __launch_bounds__(256) void sortlocal_kernel(const int* __restrict__ pairs,
                                                        const int* __restrict__ bucket_base,
                                                        const int* __restrict__ buckettotal,
                                                        int* __restrict__ sortr,
                                                        int* __restrict__ off,
                                                        float* __restrict__ dinv) {
    int b = blockIdx.x, t = threadIdx.x;
    int base = bucket_base[b];
    int cnt  = buckettotal[b];
    int c0   = b * BSZ;
    int nc   = N_NODES - c0; if (nc > BSZ) nc = BSZ;

    __shared__ int hist[BSZ];
    __shared__ int sc[256];
    for (int i = t; i < nc; i += 256) hist[i] = 0;
    __syncthreads();
    for (int i = t; i < cnt; i += 256) {
        int pc = pairs[base + i];
        atomicAdd(&hist[pc >> 17], 1);
    }
    __syncthreads();
    int e0 = 2 * t, e1 = 2 * t + 1;
    int h0 = (e0 < nc) ? hist[e0] : 0;
    int h1 = (e1 < nc) ? hist[e1] : 0;
    int ps = h0 + h1;
    sc[t] = ps;
    __syncthreads();
    for (int d = 1; d < 256; d <<= 1) {
        int x = (t >= d) ? sc[t - d] : 0;
        __syncthreads();
        sc[t] += x;
        __syncthreads();
    }
    int ex = sc[t] - ps;
    if (e0 < nc) { off[c0 + e0] = base + ex;      dinv[c0 + e0] = rsqrtf((float)h0 + 1.f); }
    if (e1 < nc) { off[c0 + e1] = base + ex + h0; dinv[c0 + e1] = rsqrtf((float)h1 + 1.f); }
    __syncthreads();
    if (e0 < nc) hist[e0] = base + ex;
    if (e1 < nc) hist[e1] = base + ex + h0;
    __syncthreads();
    for (int i = t; i < cnt; i += 256) {
        int pc = pairs[base + i];
        int pos = atomicAdd(&hist[pc >> 17], 1);
        sortr[pos] = pc & ROWMASK;
    }
}

// ---------------------------------------------------------------------------
// W pre-pack (fragment-major fp16 for mfma_f32_16x16x32_f16) + zero pooled/gcnt
__global__ __launch_bounds__(256) void wpack_zero_kernel(const float* __restrict__ W1,
                                                         const float* __restrict__ W2,
                                                         _Float16* __restrict__ Wp1,
                                                         _Float16* __restrict__ Wp2,
                                                         float* __restrict__ pooled,
                                                         float* __restrict__ gcnt) {
    int tid = blockIdx.x * 256 + threadIdx.x;   // 0..4095
    for (int i = tid; i < N_GRAPHS * 128 + N_GRAPHS; i += 4096) {
        if (i < N_GRAPHS * 128) pooled[i] = 0.f;
        else gcnt[i - N_GRAPHS * 128] = 0.f;
    }
    const float* W = (tid < 2048) ? W1 : W2;
    _Float16*   Wp = (tid < 2048) ? Wp1 : Wp2;
    int t = tid & 2047;
    int f = t >> 6, lane = t & 63;
    int j = f >> 2, s = f & 3;
    int kb = s * 32 + (lane >> 4) * 8;
    int c  = j * 16 + (lane & 15);
#pragma unroll
    for (int i = 0; i < 8; ++i)
        Wp[(size_t)t * 8 + i] = (_Float16)W[(kb + i) * 128 + c];
}

// ---------------------------------------------------------------------------
// MFMA GEMM: out8[n][:] = fp8( dinv[n] * (X[n][:] @ W) )
// FP16IN=0: X is fp32; FP16IN=1: X is fp16. Output fp8 e4m3 (gather operand).
template<int FP16IN>
__global__ __launch_bounds__(256) void gemm_mfma_kernel(const void* __restrict__ Xv,
                                                        const _Float16* __restrict__ Wp,
                                                        const float* __restrict__ dinv,
                                                        unsigned char* __restrict__ out8) {
    __shared__ _Float16 Wl[16384];
    {
        const float4* src = (const float4*)Wp;
        float4* dst = (float4*)Wl;
        for (int i = threadIdx.x; i < 2048; i += 256) dst[i] = src[i];
    }
    __syncthreads();

    int wv = threadIdx.x >> 6, lane = threadIdx.x & 63;
    int tile = blockIdx.x * 4 + wv;
    if (tile >= N_NODES / 16) return;
    int n0 = tile * 16;
    int m = lane & 15, b = lane >> 4;

    f16x8 a[4];
    if (FP16IN) {
        const _Float16* X = (const _Float16*)Xv;
        const _Float16* base = X + (size_t)(n0 + m) * 128 + b * 8;
#pragma unroll
        for (int s = 0; s < 4; ++s) a[s] = *(const f16x8*)(base + s * 32);
    } else {
        const float* X = (const float*)Xv;
        const float* base = X + (size_t)(n0 + m) * 128 + b * 8;
#pragma unroll
        for (int s = 0; s < 4; ++s) {
            float4 u = *(const float4*)(base + s * 32);
            float4 v = *(const float4*)(base + s * 32 + 4);
            f16x8 tt;
            tt[0] = (_Float16)u.x; tt[1] = (_Float16)u.y;
            tt[2] = (_Float16)u.z; tt[3] = (_Float16)u.w;
            tt[4] = (_Float16)v.x; tt[5] = (_Float16)v.y;
            tt[6] = (_Float16)v.z; tt[7] = (_Float16)v.w;
            a[s] = tt;
        }
    }

    f32x4 acc[8];
#pragma unroll
    for (int j = 0; j < 8; ++j) acc[j] = (f32x4){0.f, 0.f, 0.f, 0.f};
#pragma unroll
    for (int j = 0; j < 8; ++j)
#pragma unroll
        for (int s = 0; s < 4; ++s) {
            f16x8 bf = *(const f16x8*)&Wl[(j * 4 + s) * 512 + lane * 8];
            acc[j] = __builtin_amdgcn_mfma_f32_16x16x32_f16(a[s], bf, acc[j], 0, 0, 0);
        }

    // D layout: row = b*4 + reg, col = j*16 + m
    float dv0 = dinv[n0 + b * 4 + 0];
    float dv1 = dinv[n0 + b * 4 + 1];
    float dv2 = dinv[n0 + b * 4 + 2];
    float dv3 = dinv[n0 + b * 4 + 3];
#pragma unroll
    for (int j = 0; j < 8; ++j) {
        unsigned char* o = out8 + (size_t)(n0 + b * 4) * 128 + j * 16 + m;
        o[0 * 128] = enc8(acc[j][0] * dv0);
        o[1 * 128] = enc8(acc[j][1] * dv1);
        o[2 * 128] = enc8(acc[j][2] * dv2);
        o[3 * 128] = enc8(acc[j][3] * dv3);
    }
}

// ---------------------------------------------------------------------------
// agg: out[c][:] = fp16( relu(dinv[c] * (sum_{r in N(c)} hs8[r][:] + hs8[c][:]) + bias) )
// 1 wave per node, NO block barrier (proven delivered-BW floor structure).
// fp8 rows: 128B per row, ushort (2 ch) per lane.
__global__ __launch_bounds__(256) void agg_kernel(const unsigned char* __restrict__ hs8,
                                                  const int* __restrict__ sortr,
                                                  const int* __restrict__ off,
                                                  const float* __restrict__ dinv,
                                                  const float* __restrict__ bias,
                                                  __half* __restrict__ out) {
    int wid = (blockIdx.x * 256 + threadIdx.x) >> 6;
    int lane = threadIdx.x & 63;
    if (wid >= N_NODES) return;
    const int c = wid;
    const int e0 = off[c], e1 = off[c + 1];
    const size_t bo = 2 * (size_t)lane;   // byte offset of this lane's 2 channels

    f32x2 s = dec8x2(*(const unsigned short*)(hs8 + (size_t)c * 128 + bo));
    float a0x = s[0], a0y = s[1];
    float a1x = 0.f, a1y = 0.f, a2x = 0.f, a2y = 0.f, a3x = 0.f, a3y = 0.f;

    int e = e0;
    for (; e + 4 <= e1; e += 4) {
        int r0 = sortr[e + 0], r1 = sortr[e + 1];
        int r2 = sortr[e + 2], r3 = sortr[e + 3];
        f32x2 v0 = dec8x2(*(const unsigned short*)(hs8 + (size_t)r0 * 128 + bo));
        f32x2 v1 = dec8x2(*(const unsigned short*)(hs8 + (size_t)r1 * 128 + bo));
        f32x2 v2 = dec8x2(*(const unsigned short*)(hs8 + (size_t)r2 * 128 + bo));
        f32x2 v3 = dec8x2(*(const unsigned short*)(hs8 + (size_t)r3 * 128 + bo));
        a0x += v0[0]; a0y += v0[1];
        a1x += v1[0]; a1y += v1[1];
        a2x += v2[0]; a2y += v2[1];
        a3x += v3[0]; a3y += v3[1];
    }
    for (; e < e1; ++e) {
        int r0 = sortr[e];
        f32x2 v0 = dec8x2(*(const unsigned short*)(hs8 + (size_t)r0 * 128 + bo));
        a0x += v0[0]; a0y += v0[1];
    }
    float ax = (a0x + a1x) + (a2x + a3x);
    float ay = (a0y + a1y) + (a2y + a3y);

    float dv = dinv[c];
    float2 bb = *(const float2*)&bias[2 * lane];
    float rx = fmaxf(fmaf(ax, dv, bb.x), 0.f);
    float ry = fmaxf(fmaf(ay, dv, bb.y), 0.f);
    *(__half2*)&out[(size_t)c * 128 + 2 * lane] = __floats2half2_rn(rx, ry);
}

// ---------------------------------------------------------------------------
// mean-pool stage 1 (fp16 input): per-wave chunk of 32 sorted nodes
__global__ __launch_bounds__(256) void pool_kernel(const __half* __restrict__ h,
                                                   const int* __restrict__ batch,
                                                   float* __restrict__ pooled,
                                                   float* __restrict__ gcnt) {
    int wid = (blockIdx.x * 256 + threadIdx.x) >> 6;
    int lane = threadIdx.x & 63;
    long n0 = (long)wid * 32;
    if (n0 >= N_NODES) return;
    long n1 = n0 + 32;
    if (n1 > N_NODES) n1 = N_NODES;
    const long chb = 2 * lane;

    int g = batch[n0];
    float ax = 0.f, ay = 0.f;
    int run = 0;
    for (long n = n0; n < n1; ++n) {
        int gn = batch[n];
        if (gn != g) {   // wave-uniform branch (batch is sorted)
            atomicAdd(&pooled[g * 128 + chb], ax);
            atomicAdd(&pooled[g * 128 + chb + 1], ay);
            if (lane == 0) atomicAdd(&gcnt[g], (float)run);
            g = gn; ax = 0.f; ay = 0.f; run = 0;
        }
        float2 v = __half22float2(*(const __half2*)&h[n * 128 + chb]);
        ax += v.x; ay += v.y; run++;
    }
    atomicAdd(&pooled[g * 128 + chb], ax);
    atomicAdd(&pooled[g * 128 + chb + 1], ay);
    if (lane == 0) atomicAdd(&gcnt[g], (float)run);
}

// final: out[g][o] = (pooled[g][:]/cnt) @ Wlin[:,o] + blin[o]
__global__ void final_kernel(const float* __restrict__ pooled,
                             const float* __restrict__ gcnt,
                             const float* __restrict__ Wlin,
                             const float* __restrict__ blin,
                             float* __restrict__ out) {
    int t = threadIdx.x;
    if (t >= N_GRAPHS * 2) return;
    int g = t >> 1, o = t & 1;
    float c = gcnt[g];
    if (c < 1.f) c = 1.f;
    float s = 0.f;
    for (int k = 0; k < 128; ++k)
        s += (pooled[g * 128 + k] / c) * Wlin[k * 2 + o];
    out[g * 2 + o] = s + blin[o];
}

// ---------------------------------------------------------------------------
extern "C" void kernel_launch(void* const* d_in, const int* in_sizes, int n_in,
                              void* d_out, int out_size, void* d_ws, size_t ws_size,
                              hipStream_t stream) {
    const float* x     = (const float*)d_in[0];
    const int*   row   = (const int*)d_in[1];
    const int*   col   = row + N_EDGES;
    const int*   batch = (const int*)d_in[2];
    const float* W1    = (const float*)d_in[3];
    const float* b1    = (const float*)d_in[4];
    const float* W2    = (const float*)d_in[5];
    const float* b2    = (const float*)d_in[6];
    const float* Wlin  = (const float*)d_in[7];
    const float* blin  = (const float*)d_in[8];
    float* out = (float*)d_out;

    char* w = (char*)d_ws;
    size_t p = 0;
    auto alloc = [&](size_t bytes) -> void* {
        void* r = w + p;
        p += (bytes + 511) & ~(size_t)511;
        return r;
    };
    int*           off         = (int*)alloc((size_t)(N_NODES + 1) * 4);
    float*         dinv        = (float*)alloc((size_t)N_NODES * 4);
    int*           sortr       = (int*)alloc((size_t)N_EDGES * 4);
    int*           pairs       = (int*)alloc((size_t)N_EDGES * 4);
    int*           blockcnt    = (int*)alloc((size_t)NBLK * NB * 4);
    int*           buckettotal = (int*)alloc((size_t)NB * 4);
    int*           bucket_base = (int*)alloc((size_t)(NB + 1) * 4);
    _Float16*      Wp1         = (_Float16*)alloc((size_t)128 * 128 * 2);
    _Float16*      Wp2         = (_Float16*)alloc((size_t)128 * 128 * 2);
    unsigned char* hs8         = (unsigned char*)alloc((size_t)N_NODES * 128);
    unsigned char* hs8b        = (unsigned char*)alloc((size_t)N_NODES * 128);
    __half*        h2          = (__half*)alloc((size_t)N_NODES * 128 * 2);
    __half*        hbuf        = (__half*)alloc((size_t)N_NODES * 128 * 2);
    float*         pooled      = (float*)alloc((size_t)N_GRAPHS * 128 * 4);
    float*         gcnt       = (float*)alloc((size_t)N_GRAPHS * 4);
    (void)ws_size; (void)in_sizes; (void)n_in; (void)out_size;

    // CSR build (deterministic binned counting sort) + weight pack + zero
    sortcount_kernel<<<NBLK, 256, 0, stream>>>((const int4*)col, blockcnt);
    sortscan_kernel<<<NB, 256, 0, stream>>>(blockcnt, buckettotal);
    sortbase_kernel<<<1, 256, 0, stream>>>(buckettotal, bucket_base, off);
    sortscatter_kernel<<<NBLK, 256, 0, stream>>>((const int4*)row, (const int4*)col,
                                                 blockcnt, bucket_base, pairs);
    sortlocal_kernel<<<NB, 256, 0, stream>>>(pairs, bucket_base, buckettotal,
                                             sortr, off, dinv);
    wpack_zero_kernel<<<16, 256, 0, stream>>>(W1, W2, Wp1, Wp2, pooled, gcnt);

    // layer 1: GEMM (fp32 in, fp8 out) -> gather (fp8 in, fp16 out)
    gemm_mfma_kernel<0><<<(N_NODES / 16 + 3) / 4, 256, 0, stream>>>(x, Wp1, dinv, hs8);
    agg_kernel<<<(N_NODES * 64 + 255) / 256, 256, 0, stream>>>(hs8, sortr, off, dinv, b1, h2);
    // layer 2: GEMM (fp16 in, fp8 out) -> gather (fp8 in, fp16 out)
    gemm_mfma_kernel<1><<<(N_NODES / 16 + 3) / 4, 256, 0, stream>>>(h2, Wp2, dinv, hs8b);
    agg_kernel<<<(N_NODES * 64 + 255) / 256, 256, 0, stream>>>(hs8b, sortr, off, dinv, b2, hbuf);

    // pool + classifier
    pool_kernel<<<(((N_NODES + 31) / 32) * 64 + 255) / 256, 256, 0, stream>>>(hbuf, batch, pooled, gcnt);
    final_kernel<<<1, 128, 0, stream>>>(pooled, gcnt, Wlin, blin, out);
}